// Round 2
// baseline (3078.741 us; speedup 1.0000x reference)
//
#include <hip/hip_runtime.h>
#include <stdint.h>
#include <math.h>

typedef unsigned short u16;
typedef short s16x8 __attribute__((ext_vector_type(8)));
typedef float f32x4 __attribute__((ext_vector_type(4)));

// ---- problem constants ----
#define BB 2
#define SS 2048
#define DIM 2048
#define NH 16
#define NOPE 128
#define ROPED 64
#define VH 128
#define KVR 512
#define NE 8
#define MINTER 1408
#define SHI 2816
#define TT 4096          // B*S
#define QD 192           // NOPE+ROPE
#define POOLR 9216       // max padded token-expert pairs (8192 + 8*128)

__device__ __forceinline__ u16 f2bf(float f) {
  unsigned u = __builtin_bit_cast(unsigned, f);
  u += 0x7fffu + ((u >> 16) & 1u);   // RNE
  return (u16)(u >> 16);
}
__device__ __forceinline__ float bf2f(u16 h) {
  return __builtin_bit_cast(float, ((unsigned)h) << 16);
}
__device__ __forceinline__ void split2(float v, u16& hi, u16& lo) {
  u16 h = f2bf(v);
  hi = h;
  lo = f2bf(v - bf2f(h));
}

// ---------------- converts ----------------
__global__ void split_f32(const float* __restrict__ in, u16* __restrict__ hi,
                          u16* __restrict__ lo, int n) {
  int i = blockIdx.x * 256 + threadIdx.x;
  if (i < n) split2(in[i], hi[i], lo[i]);
}
__global__ void cvt3_bf16(const float* __restrict__ a, const float* __restrict__ b,
                          const float* __restrict__ c, u16* __restrict__ oa,
                          u16* __restrict__ ob, u16* __restrict__ oc, int n) {
  int i = blockIdx.x * 256 + threadIdx.x;
  if (i < n) { oa[i] = f2bf(a[i]); ob[i] = f2bf(b[i]); oc[i] = f2bf(c[i]); }
}
__global__ void cvt_bf16(const float* __restrict__ a, u16* __restrict__ o, int n) {
  int i = blockIdx.x * 256 + threadIdx.x;
  if (i < n) o[i] = f2bf(a[i]);
}
// fused [w1;w3] per-expert conversion: w13[e][row][col], row<1408 -> ew1, else ew3
__global__ void cvt_w13(const float* __restrict__ ew1, const float* __restrict__ ew3,
                        u16* __restrict__ w13) {
  int i = blockIdx.x * 256 + threadIdx.x;     // over 8*2816*2048 = 46137344
  int col = i & 2047;
  int r = i >> 11;                            // e*2816 + row
  int e = r / 2816;
  int row = r - e * 2816;
  float v;
  if (row < MINTER) v = ew1[((size_t)e * MINTER + row) * 2048 + col];
  else              v = ew3[((size_t)e * MINTER + (row - MINTER)) * 2048 + col];
  w13[(size_t)i] = f2bf(v);
}
// wkv_a (576x2048) -> padded 640x2048 split (zero rows 576..639)
__global__ void split_wkva(const float* __restrict__ in, u16* __restrict__ hi,
                           u16* __restrict__ lo) {
  int i = blockIdx.x * 256 + threadIdx.x;  // over 640*2048
  int row = i >> 11;
  float v = (row < 576) ? in[(size_t)row * 2048 + (i & 2047)] : 0.f;
  split2(v, hi[i], lo[i]);
}
__global__ void zero_u32(unsigned* __restrict__ p, int n) {
  int i = blockIdx.x * 256 + threadIdx.x;
  if (i < n) p[i] = 0u;
}

// ---------------- rmsnorm (D=2048) f32 -> split bf16 pair ----------------
__global__ __launch_bounds__(256) void rmsnorm_split(const float* __restrict__ x,
                                                     const float* __restrict__ w,
                                                     u16* __restrict__ oh,
                                                     u16* __restrict__ ol) {
  int t = blockIdx.x;
  const float* xr = x + (size_t)t * DIM;
  float ss = 0.f;
#pragma unroll
  for (int i = 0; i < 8; i++) { float v = xr[threadIdx.x + i * 256]; ss += v * v; }
#pragma unroll
  for (int off = 32; off; off >>= 1) ss += __shfl_xor(ss, off, 64);
  __shared__ float red[4];
  if ((threadIdx.x & 63) == 0) red[threadIdx.x >> 6] = ss;
  __syncthreads();
  ss = red[0] + red[1] + red[2] + red[3];
  float rstd = rsqrtf(ss * (1.f / DIM) + 1e-6f);
#pragma unroll
  for (int i = 0; i < 8; i++) {
    int c = threadIdx.x + i * 256;
    float v = xr[c] * rstd * w[c];
    split2(v, oh[(size_t)t * DIM + c], ol[(size_t)t * DIM + c]);
  }
}

// ---------------- rmsnorm f32 -> bf16 (FFN input) ----------------
__global__ __launch_bounds__(256) void rmsnorm_bf16(const float* __restrict__ x,
                                                    const float* __restrict__ w,
                                                    u16* __restrict__ out) {
  int t = blockIdx.x;
  const float* xr = x + (size_t)t * DIM;
  float ss = 0.f;
#pragma unroll
  for (int i = 0; i < 8; i++) { float v = xr[threadIdx.x + i * 256]; ss += v * v; }
#pragma unroll
  for (int off = 32; off; off >>= 1) ss += __shfl_xor(ss, off, 64);
  __shared__ float red[4];
  if ((threadIdx.x & 63) == 0) red[threadIdx.x >> 6] = ss;
  __syncthreads();
  ss = red[0] + red[1] + red[2] + red[3];
  float rstd = rsqrtf(ss * (1.f / DIM) + 1e-6f);
#pragma unroll
  for (int i = 0; i < 8; i++) {
    int c = threadIdx.x + i * 256;
    out[(size_t)t * DIM + c] = f2bf(xr[c] * rstd * w[c]);
  }
}

// ---------------- kv: rmsnorm(512) + rope(k_pe), f32 in -> split outs ----------------
__global__ __launch_bounds__(256) void kv_norm_rope_split(const float* __restrict__ kv,
                                                          const float* __restrict__ w,
                                                          const float* __restrict__ fcos,
                                                          const float* __restrict__ fsin,
                                                          u16* __restrict__ ckvh,
                                                          u16* __restrict__ ckvl,
                                                          u16* __restrict__ peh,
                                                          u16* __restrict__ pel) {
  int t = blockIdx.x;
  int pos = t & (SS - 1);
  const float* kr = kv + (size_t)t * 640;
  float v0 = kr[threadIdx.x], v1 = kr[threadIdx.x + 256];
  float ss = v0 * v0 + v1 * v1;
#pragma unroll
  for (int off = 32; off; off >>= 1) ss += __shfl_xor(ss, off, 64);
  __shared__ float red[4];
  if ((threadIdx.x & 63) == 0) red[threadIdx.x >> 6] = ss;
  __syncthreads();
  ss = red[0] + red[1] + red[2] + red[3];
  float rstd = rsqrtf(ss * (1.f / KVR) + 1e-6f);
  float a0 = v0 * rstd * w[threadIdx.x];
  float a1 = v1 * rstd * w[threadIdx.x + 256];
  split2(a0, ckvh[(size_t)t * KVR + threadIdx.x], ckvl[(size_t)t * KVR + threadIdx.x]);
  split2(a1, ckvh[(size_t)t * KVR + threadIdx.x + 256], ckvl[(size_t)t * KVR + threadIdx.x + 256]);
  if (threadIdx.x < 32) {
    int i = threadIdx.x;
    float x1 = kr[KVR + 2 * i], x2 = kr[KVR + 2 * i + 1];
    float c = fcos[pos * 32 + i], s = fsin[pos * 32 + i];
    split2(x1 * c - x2 * s, peh[(size_t)t * 64 + 2 * i], pel[(size_t)t * 64 + 2 * i]);
    split2(x1 * s + x2 * c, peh[(size_t)t * 64 + 2 * i + 1], pel[(size_t)t * 64 + 2 * i + 1]);
  }
}

// ---------------- rope on q_pe slices (f32 q, in-place) ----------------
__global__ void rope_qf(float* __restrict__ q, const float* __restrict__ fcos,
                        const float* __restrict__ fsin) {
  int idx = blockIdx.x * 256 + threadIdx.x;  // TT*NH*32
  if (idx >= TT * NH * 32) return;
  int i = idx & 31;
  int rem = idx >> 5;
  int h = rem & 15, t = rem >> 4;
  int pos = t & (SS - 1);
  size_t base = (size_t)t * (NH * QD) + h * QD + NOPE + 2 * i;
  float x1 = q[base], x2 = q[base + 1];
  float c = fcos[pos * 32 + i], s = fsin[pos * 32 + i];
  q[base] = x1 * c - x2 * s;
  q[base + 1] = x1 * s + x2 * c;
}

// ---------------- residual: h += x; out = h ----------------
__global__ void add_residual(float* __restrict__ h, const float* __restrict__ x,
                             float* __restrict__ out, int n) {
  int i = blockIdx.x * 256 + threadIdx.x;
  if (i < n) {
    float v = h[i] + x[i];
    h[i] = v;
    out[i] = v;
  }
}

// ---------------- router, fully f32 from h (inline rmsnorm) ----------------
__global__ __launch_bounds__(256) void router_f32(const float* __restrict__ h,
                                                  const float* __restrict__ wn,
                                                  const float* __restrict__ rw,
                                                  float* __restrict__ gates) {
  int t = blockIdx.x;
  const float* xr = h + (size_t)t * DIM;
  float xv[8];
  float ss = 0.f;
#pragma unroll
  for (int i = 0; i < 8; i++) { xv[i] = xr[threadIdx.x + i * 256]; ss += xv[i] * xv[i]; }
#pragma unroll
  for (int off = 32; off; off >>= 1) ss += __shfl_xor(ss, off, 64);
  __shared__ float red4[4];
  if ((threadIdx.x & 63) == 0) red4[threadIdx.x >> 6] = ss;
  __syncthreads();
  ss = red4[0] + red4[1] + red4[2] + red4[3];
  float rstd = rsqrtf(ss * (1.f / DIM) + 1e-6f);
  float p[8];
#pragma unroll
  for (int e = 0; e < 8; e++) p[e] = 0.f;
#pragma unroll
  for (int i = 0; i < 8; i++) {
    int c = threadIdx.x + i * 256;
    float nv = xv[i] * rstd * wn[c];
#pragma unroll
    for (int e = 0; e < 8; e++) p[e] += nv * rw[e * DIM + c];
  }
  __shared__ float red[8 * 256];
#pragma unroll
  for (int e = 0; e < 8; e++) red[e * 256 + threadIdx.x] = p[e];
  __syncthreads();
  for (int st = 128; st > 0; st >>= 1) {
    if (threadIdx.x < st) {
#pragma unroll
      for (int e = 0; e < 8; e++) red[e * 256 + threadIdx.x] += red[e * 256 + threadIdx.x + st];
    }
    __syncthreads();
  }
  if (threadIdx.x == 0) {
    float lg[8], mx = -1e30f;
#pragma unroll
    for (int e = 0; e < 8; e++) { lg[e] = red[e * 256]; mx = fmaxf(mx, lg[e]); }
#pragma unroll
    for (int e = 0; e < 8; e++) lg[e] = expf(lg[e] - mx);
    int i1 = 0;
#pragma unroll
    for (int e = 1; e < 8; e++) if (lg[e] > lg[i1]) i1 = e;
    int i2 = -1;
#pragma unroll
    for (int e = 0; e < 8; e++) if (e != i1 && (i2 < 0 || lg[e] > lg[i2])) i2 = e;
    float v1 = lg[i1], v2 = lg[i2], vs = v1 + v2;
#pragma unroll
    for (int e = 0; e < 8; e++) gates[t * 8 + e] = 0.f;
    gates[t * 8 + i1] = v1 / vs;
    gates[t * 8 + i2] = v2 / vs;
  }
}

// ---------------- MoE routing compaction (device-side, graph-safe) ----------------
__global__ void moe_count(const float* __restrict__ gates, unsigned* __restrict__ cnt) {
  int t = blockIdx.x * 256 + threadIdx.x;
  if (t >= TT) return;
#pragma unroll
  for (int e = 0; e < 8; e++)
    if (gates[t * 8 + e] > 0.f) atomicAdd(&cnt[e], 1u);
}
__global__ void moe_prefix(const unsigned* __restrict__ cnt, unsigned* __restrict__ base) {
  if (threadIdx.x == 0 && blockIdx.x == 0) {
    unsigned o = 0;
#pragma unroll
    for (int e = 0; e < 8; e++) {
      base[e] = o;
      o += (cnt[e] + 127u) & ~127u;   // 128-pad each expert segment
    }
    base[8] = o;
  }
}
__global__ void moe_assign(const float* __restrict__ gates, const unsigned* __restrict__ base,
                           unsigned* __restrict__ cnt2, int* __restrict__ pool_tok,
                           float* __restrict__ pool_gate) {
  int t = blockIdx.x * 256 + threadIdx.x;
  if (t >= TT) return;
#pragma unroll
  for (int e = 0; e < 8; e++) {
    float g = gates[t * 8 + e];
    if (g > 0.f) {
      unsigned p = atomicAdd(&cnt2[e], 1u);
      pool_tok[base[e] + p] = t;
      pool_gate[base[e] + p] = g;
    }
  }
}

// ---------------- silu(g1)*g3, bf16 in/out ----------------
__global__ void silu_mul(const u16* __restrict__ g1, const u16* __restrict__ g3,
                         u16* __restrict__ out, int n) {
  int i = blockIdx.x * 256 + threadIdx.x;
  if (i < n) {
    float a = bf2f(g1[i]), c = bf2f(g3[i]);
    out[i] = f2bf(a / (1.f + expf(-a)) * c);
  }
}
// silu over fused [g1;g3] pool rows
__global__ void silu_mul_pool(const u16* __restrict__ g13, u16* __restrict__ h1,
                              const unsigned* __restrict__ base) {
  unsigned row = blockIdx.y;
  if (row >= base[8]) return;
  int col = blockIdx.x * 256 + threadIdx.x;
  if (col >= MINTER) return;
  float a = bf2f(g13[(size_t)row * SHI + col]);
  float c = bf2f(g13[(size_t)row * SHI + MINTER + col]);
  h1[(size_t)row * MINTER + col] = f2bf(a / (1.f + expf(-a)) * c);
}

// ---------------- GEMM: C[M,N] = A[M,K] @ W[N,K]^T, bf16 in, f32 acc ----------------
enum { EPI_BF16 = 0, EPI_F32 = 1, EPI_ADD = 3 };

template <int EPI>
__global__ __launch_bounds__(256) void gemm_bt(const u16* __restrict__ A,
                                               const u16* __restrict__ W,
                                               void* __restrict__ C,
                                               int M, int N, int K) {
  __shared__ u16 As[128 * 40];
  __shared__ u16 Ws[128 * 40];
  int tid = threadIdx.x;
  int lane = tid & 63;
  int l16 = lane & 15, quad = lane >> 4;
  int wv = tid >> 6;
  int wrow = wv & 1, wcol = wv >> 1;
  int bm = blockIdx.y * 128, bn = blockIdx.x * 128;
  const u16* Ab = A + (size_t)bm * K;
  const u16* Wb = W + (size_t)bn * K;
  int srow = tid >> 2, scol = (tid & 3) * 8;

  f32x4 acc[4][4];
#pragma unroll
  for (int mt = 0; mt < 4; mt++)
#pragma unroll
    for (int nt = 0; nt < 4; nt++) acc[mt][nt] = (f32x4){0.f, 0.f, 0.f, 0.f};

  for (int k0 = 0; k0 < K; k0 += 32) {
    s16x8 a0 = *(const s16x8*)&Ab[(size_t)srow * K + k0 + scol];
    s16x8 a1 = *(const s16x8*)&Ab[(size_t)(srow + 64) * K + k0 + scol];
    s16x8 w0 = *(const s16x8*)&Wb[(size_t)srow * K + k0 + scol];
    s16x8 w1 = *(const s16x8*)&Wb[(size_t)(srow + 64) * K + k0 + scol];
    __syncthreads();
    *(s16x8*)&As[srow * 40 + scol] = a0;
    *(s16x8*)&As[(srow + 64) * 40 + scol] = a1;
    *(s16x8*)&Ws[srow * 40 + scol] = w0;
    *(s16x8*)&Ws[(srow + 64) * 40 + scol] = w1;
    __syncthreads();
    s16x8 af[4], wf[4];
#pragma unroll
    for (int mt = 0; mt < 4; mt++)
      af[mt] = *(const s16x8*)&As[(wrow * 64 + mt * 16 + l16) * 40 + quad * 8];
#pragma unroll
    for (int nt = 0; nt < 4; nt++)
      wf[nt] = *(const s16x8*)&Ws[(wcol * 64 + nt * 16 + l16) * 40 + quad * 8];
#pragma unroll
    for (int mt = 0; mt < 4; mt++)
#pragma unroll
      for (int nt = 0; nt < 4; nt++)
        acc[mt][nt] = __builtin_amdgcn_mfma_f32_16x16x32_bf16(af[mt], wf[nt], acc[mt][nt], 0, 0, 0);
  }
#pragma unroll
  for (int mt = 0; mt < 4; mt++) {
#pragma unroll
    for (int r = 0; r < 4; r++) {
      int row = bm + wrow * 64 + mt * 16 + quad * 4 + r;
#pragma unroll
      for (int nt = 0; nt < 4; nt++) {
        int col = bn + wcol * 64 + nt * 16 + l16;
        float v = acc[mt][nt][r];
        size_t idx = (size_t)row * N + col;
        if constexpr (EPI == EPI_BF16) ((u16*)C)[idx] = f2bf(v);
        else if constexpr (EPI == EPI_F32) ((float*)C)[idx] = v;
        else ((float*)C)[idx] += v;
      }
    }
  }
}

// ---------------- MoE gather GEMM (w1||w3 fused): g13[pool] = nh[tok] @ w13_e^T ----------------
__global__ __launch_bounds__(256) void gemm_moe_w13(const u16* __restrict__ A,   // nh_b [TT,2048]
                                                    const u16* __restrict__ W,   // w13 [8][2816][2048]
                                                    u16* __restrict__ C,         // g13 pool [POOLR][2816]
                                                    const int* __restrict__ pool_tok,
                                                    const unsigned* __restrict__ cnt,
                                                    const unsigned* __restrict__ base) {
  int e = blockIdx.z;
  int bm = blockIdx.y * 128;
  if ((unsigned)bm >= cnt[e]) return;       // tile fully past this expert's tokens
  int pb = (int)base[e] + bm;
  const int K = 2048;
  __shared__ u16 As[128 * 40];
  __shared__ u16 Ws[128 * 40];
  int tid = threadIdx.x;
  int lane = tid & 63;
  int l16 = lane & 15, quad = lane >> 4;
  int wv = tid >> 6;
  int wrow = wv & 1, wcol = wv >> 1;
  int bn = blockIdx.x * 128;
  const u16* Wb = W + (size_t)e * SHI * 2048 + (size_t)bn * K;
  int srow = tid >> 2, scol = (tid & 3) * 8;
  const u16* Ap0 = A + (size_t)pool_tok[pb + srow] * K;        // gathered rows
  const u16* Ap1 = A + (size_t)pool_tok[pb + srow + 64] * K;

  f32x4 acc[4][4];
#pragma unroll
  for (int mt = 0; mt < 4; mt++)
#pragma unroll
    for (int nt = 0; nt < 4; nt++) acc[mt][nt] = (f32x4){0.f, 0.f, 0.f, 0.f};

  for (int k0 = 0; k0 < K; k0 += 32) {
    s16x8 a0 = *(const s16x8*)&Ap0[k0 + scol];
    s16x8 a1 = *(const s16x8*)&Ap1[k0 + scol];
    s16x8 w0 = *(const s16x8*)&Wb[(size_t)srow * K + k0 + scol];
    s16x8 w1 = *(const s16x8*)&Wb[(size_t)(srow + 64) * K + k0 + scol];
    __syncthreads();
    *(s16x8*)&As[srow * 40 + scol] = a0;
    *(s16x8*)&As[(srow + 64) * 40 + scol] = a1;
    *(s16x8*)&Ws[srow * 40 + scol] = w0;
    *(s16x8*)&Ws[(srow + 64) * 40 + scol] = w1;
    __syncthreads();
    s16x8 af[4], wf[4];
#pragma unroll
    for (int mt = 0; mt < 4; mt++)
      af[mt] = *(const s16x8*)&As[(wrow * 64 + mt * 16 + l16) * 40 + quad * 8];
#pragma unroll
    for (int nt = 0; nt < 4; nt++)
      wf[nt] = *(const s16x8*)&Ws[(wcol * 64 + nt * 16 + l16) * 40 + quad * 8];
#pragma unroll
    for (int mt = 0; mt < 4; mt++)
#pragma unroll
      for (int nt = 0; nt < 4; nt++)
        acc[mt][nt] = __builtin_amdgcn_mfma_f32_16x16x32_bf16(af[mt], wf[nt], acc[mt][nt], 0, 0, 0);
  }
#pragma unroll
  for (int mt = 0; mt < 4; mt++) {
#pragma unroll
    for (int r = 0; r < 4; r++) {
      int row = pb + wrow * 64 + mt * 16 + quad * 4 + r;
#pragma unroll
      for (int nt = 0; nt < 4; nt++) {
        int col = bn + wcol * 64 + nt * 16 + l16;
        C[(size_t)row * SHI + col] = f2bf(acc[mt][nt][r]);
      }
    }
  }
}

// ---------------- MoE down-proj GEMM with gated atomic scatter into out ----------------
__global__ __launch_bounds__(256) void gemm_moe_w2(const u16* __restrict__ A,   // h1 pool [POOLR][1408]
                                                   const u16* __restrict__ W,   // w2 [8][2048][1408]
                                                   float* __restrict__ out,     // [TT][2048]
                                                   const int* __restrict__ pool_tok,
                                                   const float* __restrict__ pool_gate,
                                                   const unsigned* __restrict__ cnt,
                                                   const unsigned* __restrict__ base) {
  int e = blockIdx.z;
  int bm = blockIdx.y * 128;
  if ((unsigned)bm >= cnt[e]) return;
  int pb = (int)base[e] + bm;
  const int K = MINTER;  // 1408
  __shared__ u16 As[128 * 40];
  __shared__ u16 Ws[128 * 40];
  int tid = threadIdx.x;
  int lane = tid & 63;
  int l16 = lane & 15, quad = lane >> 4;
  int wv = tid >> 6;
  int wrow = wv & 1, wcol = wv >> 1;
  int bn = blockIdx.x * 128;
  const u16* Ab = A + (size_t)pb * K;
  const u16* Wb = W + (size_t)e * 2048 * MINTER + (size_t)bn * K;
  int srow = tid >> 2, scol = (tid & 3) * 8;

  f32x4 acc[4][4];
#pragma unroll
  for (int mt = 0; mt < 4; mt++)
#pragma unroll
    for (int nt = 0; nt < 4; nt++) acc[mt][nt] = (f32x4){0.f, 0.f, 0.f, 0.f};

  for (int k0 = 0; k0 < K; k0 += 32) {
    s16x8 a0 = *(const s16x8*)&Ab[(size_t)srow * K + k0 + scol];
    s16x8 a1 = *(const s16x8*)&Ab[(size_t)(srow + 64) * K + k0 + scol];
    s16x8 w0 = *(const s16x8*)&Wb[(size_t)srow * K + k0 + scol];
    s16x8 w1 = *(const s16x8*)&Wb[(size_t)(srow + 64) * K + k0 + scol];
    __syncthreads();
    *(s16x8*)&As[srow * 40 + scol] = a0;
    *(s16x8*)&As[(srow + 64) * 40 + scol] = a1;
    *(s16x8*)&Ws[srow * 40 + scol] = w0;
    *(s16x8*)&Ws[(srow + 64) * 40 + scol] = w1;
    __syncthreads();
    s16x8 af[4], wf[4];
#pragma unroll
    for (int mt = 0; mt < 4; mt++)
      af[mt] = *(const s16x8*)&As[(wrow * 64 + mt * 16 + l16) * 40 + quad * 8];
#pragma unroll
    for (int nt = 0; nt < 4; nt++)
      wf[nt] = *(const s16x8*)&Ws[(wcol * 64 + nt * 16 + l16) * 40 + quad * 8];
#pragma unroll
    for (int mt = 0; mt < 4; mt++)
#pragma unroll
      for (int nt = 0; nt < 4; nt++)
        acc[mt][nt] = __builtin_amdgcn_mfma_f32_16x16x32_bf16(af[mt], wf[nt], acc[mt][nt], 0, 0, 0);
  }
#pragma unroll
  for (int mt = 0; mt < 4; mt++) {
#pragma unroll
    for (int r = 0; r < 4; r++) {
      int prow = pb + wrow * 64 + mt * 16 + quad * 4 + r;
      float g = pool_gate[prow];
      int tok = pool_tok[prow];
      if (g > 0.f) {   // padding rows have gate==0 -> no store, no race
#pragma unroll
        for (int nt = 0; nt < 4; nt++) {
          int col = bn + wcol * 64 + nt * 16 + l16;
          unsafeAtomicAdd(&out[(size_t)tok * 2048 + col], g * acc[mt][nt][r]);
        }
      }
    }
  }
}

// ---------------- flash attention, split-bf16 (causal, d_qk=192, d_v=128) ----------------
__global__ __launch_bounds__(256) void flash_attn_split(
    const u16* __restrict__ Qh, const u16* __restrict__ Ql,
    const u16* __restrict__ KVh, const u16* __restrict__ KVl,
    const u16* __restrict__ Peh, const u16* __restrict__ Pel,
    float* __restrict__ O) {
  __shared__ u16 Ksh[32 * 200], Ksl[32 * 200];
  __shared__ u16 Vth[128 * 40], Vtl[128 * 40];
  __shared__ u16 Psh[64 * 40], Psl[64 * 40];
  int tid = threadIdx.x;
  int lane = tid & 63, wv = tid >> 6;
  int l16 = lane & 15, quad = lane >> 4;
  int qt = blockIdx.x;
  int b = blockIdx.y >> 4, h = blockIdx.y & 15;
  int tb = b * SS;
  const float kSc = 0.07216878364870322f * 1.4426950408889634f;  // 1/sqrt(192)*log2(e)

  s16x8 qfh[6], qfl[6];
  {
    int qrow = tb + qt * 64 + wv * 16 + l16;
    const u16* ph = Qh + (size_t)qrow * (NH * QD) + h * QD;
    const u16* pl = Ql + (size_t)qrow * (NH * QD) + h * QD;
#pragma unroll
    for (int s = 0; s < 6; s++) {
      qfh[s] = *(const s16x8*)&ph[s * 32 + quad * 8];
      qfl[s] = *(const s16x8*)&pl[s * 32 + quad * 8];
    }
  }
  float m_i[4], l_i[4];
#pragma unroll
  for (int r = 0; r < 4; r++) { m_i[r] = -1e30f; l_i[r] = 0.f; }
  f32x4 o_acc[8];
#pragma unroll
  for (int nt = 0; nt < 8; nt++) o_acc[nt] = (f32x4){0.f, 0.f, 0.f, 0.f};

  int nkt = 2 * qt + 2;
  for (int kt = 0; kt < nkt; kt++) {
    __syncthreads();
#pragma unroll
    for (int i = 0; i < 2; i++) {
      int c = tid + i * 256;
      int row = c >> 4, cc = (c & 15) * 8;
      size_t g = (size_t)(tb + kt * 32 + row) * 4096 + h * 256 + cc;
      *(s16x8*)&Ksh[row * 200 + cc] = *(const s16x8*)&KVh[g];
      *(s16x8*)&Ksl[row * 200 + cc] = *(const s16x8*)&KVl[g];
    }
    {
      int row = tid >> 3, cc = (tid & 7) * 8;
      size_t g = (size_t)(tb + kt * 32 + row) * 64 + cc;
      *(s16x8*)&Ksh[row * 200 + 128 + cc] = *(const s16x8*)&Peh[g];
      *(s16x8*)&Ksl[row * 200 + 128 + cc] = *(const s16x8*)&Pel[g];
    }
#pragma unroll
    for (int i = 0; i < 16; i++) {
      int idx = tid + i * 256;
      int n = idx & 127, k = idx >> 7;
      size_t g = (size_t)(tb + kt * 32 + k) * 4096 + h * 256 + 128 + n;
      Vth[n * 40 + k] = KVh[g];
      Vtl[n * 40 + k] = KVl[g];
    }
    __syncthreads();
    f32x4 sc[2];
#pragma unroll
    for (int ct = 0; ct < 2; ct++) {
      f32x4 a = (f32x4){0.f, 0.f, 0.f, 0.f};
#pragma unroll
      for (int s = 0; s < 6; s++) {
        s16x8 kh = *(const s16x8*)&Ksh[(ct * 16 + l16) * 200 + s * 32 + quad * 8];
        s16x8 kl = *(const s16x8*)&Ksl[(ct * 16 + l16) * 200 + s * 32 + quad * 8];
        a = __builtin_amdgcn_mfma_f32_16x16x32_bf16(qfh[s], kh, a, 0, 0, 0);
        a = __builtin_amdgcn_mfma_f32_16x16x32_bf16(qfh[s], kl, a, 0, 0, 0);
        a = __builtin_amdgcn_mfma_f32_16x16x32_bf16(qfl[s], kh, a, 0, 0, 0);
      }
      sc[ct] = a;
    }
    float rowmax[4];
#pragma unroll
    for (int r = 0; r < 4; r++) rowmax[r] = -1e30f;
#pragma unroll
    for (int ct = 0; ct < 2; ct++) {
#pragma unroll
      for (int r = 0; r < 4; r++) {
        float v = sc[ct][r] * kSc;
        int kg = kt * 32 + ct * 16 + l16;
        int qg = qt * 64 + wv * 16 + quad * 4 + r;
        if (kg > qg) v = -1e30f;
        sc[ct][r] = v;
        rowmax[r] = fmaxf(rowmax[r], v);
      }
    }
#pragma unroll
    for (int r = 0; r < 4; r++) {
      float v = rowmax[r];
#pragma unroll
      for (int off = 1; off < 16; off <<= 1) v = fmaxf(v, __shfl_xor(v, off, 64));
      rowmax[r] = v;
    }
    float alpha[4], rs[4];
#pragma unroll
    for (int r = 0; r < 4; r++) {
      float mn = fmaxf(m_i[r], rowmax[r]);
      alpha[r] = exp2f(m_i[r] - mn);
      m_i[r] = mn;
      rs[r] = 0.f;
    }
#pragma unroll
    for (int ct = 0; ct < 2; ct++) {
#pragma unroll
      for (int r = 0; r < 4; r++) {
        float p = exp2f(sc[ct][r] - m_i[r]);
        rs[r] += p;
        int prow = (wv * 16 + quad * 4 + r) * 40 + ct * 16 + l16;
        u16 hb = f2bf(p);
        Psh[prow] = hb;
        Psl[prow] = f2bf(p - bf2f(hb));
      }
    }
#pragma unroll
    for (int r = 0; r < 4; r++) {
      float v = rs[r];
#pragma unroll
      for (int off = 1; off < 16; off <<= 1) v += __shfl_xor(v, off, 64);
      l_i[r] = l_i[r] * alpha[r] + v;
    }
#pragma unroll
    for (int nt = 0; nt < 8; nt++)
#pragma unroll
      for (int r = 0; r < 4; r++) o_acc[nt][r] *= alpha[r];
    __syncthreads();
    s16x8 pfh = *(const s16x8*)&Psh[(wv * 16 + l16) * 40 + quad * 8];
    s16x8 pfl = *(const s16x8*)&Psl[(wv * 16 + l16) * 40 + quad * 8];
#pragma unroll
    for (int nt = 0; nt < 8; nt++) {
      s16x8 vh = *(const s16x8*)&Vth[(nt * 16 + l16) * 40 + quad * 8];
      s16x8 vl = *(const s16x8*)&Vtl[(nt * 16 + l16) * 40 + quad * 8];
      o_acc[nt] = __builtin_amdgcn_mfma_f32_16x16x32_bf16(pfh, vh, o_acc[nt], 0, 0, 0);
      o_acc[nt] = __builtin_amdgcn_mfma_f32_16x16x32_bf16(pfh, vl, o_acc[nt], 0, 0, 0);
      o_acc[nt] = __builtin_amdgcn_mfma_f32_16x16x32_bf16(pfl, vh, o_acc[nt], 0, 0, 0);
    }
  }
#pragma unroll
  for (int r = 0; r < 4; r++) {
    int trow = tb + qt * 64 + wv * 16 + quad * 4 + r;
    float inv_l = 1.f / l_i[r];
    float* op = O + (size_t)trow * 2048 + h * 128;
#pragma unroll
    for (int nt = 0; nt < 8; nt++) op[nt * 16 + l16] = o_acc[nt][r] * inv_l;
  }
}

// ---------------- host ----------------
extern "C" void kernel_launch(void* const* d_in, const int* in_sizes, int n_in,
                              void* d_out, int out_size, void* d_ws, size_t ws_size,
                              hipStream_t stream) {
  const float* x = (const float*)d_in[0];
  const float* fcos = (const float*)d_in[1];
  const float* fsin = (const float*)d_in[2];
  const float* attn_w = (const float*)d_in[3];
  const float* wq = (const float*)d_in[4];
  const float* wkva = (const float*)d_in[5];
  const float* kvnw = (const float*)d_in[6];
  const float* wkvb = (const float*)d_in[7];
  const float* wo = (const float*)d_in[8];
  const float* ffnw = (const float*)d_in[9];
  const float* rw = (const float*)d_in[10];
  const float* ew1 = (const float*)d_in[11];
  const float* ew3 = (const float*)d_in[12];
  const float* ew2 = (const float*)d_in[13];
  const float* sw1 = (const float*)d_in[14];
  const float* sw3 = (const float*)d_in[15];
  const float* sw2 = (const float*)d_in[16];
  float* out = (float*)d_out;

  char* ws = (char*)d_ws;
  size_t off = 0;
  auto alloc = [&](size_t bytes) -> char* {
    char* p = ws + off;
    off += (bytes + 255) & ~(size_t)255;
    return p;
  };
  // ---- persistent ----
  u16* wq_h = (u16*)alloc((size_t)3072 * 2048 * 2);
  u16* wq_l = (u16*)alloc((size_t)3072 * 2048 * 2);
  u16* wkva_h = (u16*)alloc((size_t)640 * 2048 * 2);
  u16* wkva_l = (u16*)alloc((size_t)640 * 2048 * 2);
  u16* wkvb_h = (u16*)alloc((size_t)4096 * 512 * 2);
  u16* wkvb_l = (u16*)alloc((size_t)4096 * 512 * 2);
  u16* wo_h = (u16*)alloc((size_t)2048 * 2048 * 2);
  u16* wo_l = (u16*)alloc((size_t)2048 * 2048 * 2);
  u16* sw1_b = (u16*)alloc((size_t)2816 * 2048 * 2);
  u16* sw3_b = (u16*)alloc((size_t)2816 * 2048 * 2);
  u16* sw2_b = (u16*)alloc((size_t)2048 * 2816 * 2);
  float* h_f = (float*)alloc((size_t)TT * 2048 * 4);
  u16* nh_b = (u16*)alloc((size_t)TT * 2048 * 2);
  float* gates_f = (float*)alloc((size_t)TT * 8 * 4);
  u16* attn_h = (u16*)alloc((size_t)TT * 2048 * 2);
  u16* attn_l = (u16*)alloc((size_t)TT * 2048 * 2);
  // routing pool (contiguous for one-shot zeroing: tok, gate, cnt, cnt2)
  int* pool_tok = (int*)alloc((size_t)POOLR * 4);      // 36864 B (256-aligned)
  float* pool_gate = (float*)alloc((size_t)POOLR * 4); // 36864 B
  unsigned* cnt = (unsigned*)alloc(32);                // -> 256 B
  unsigned* cnt2 = (unsigned*)alloc(32);               // -> 256 B
  unsigned* basep = (unsigned*)alloc(64);              // written fully by moe_prefix
  const int ZERO_WORDS = (36864 + 36864 + 256 + 256) / 4;  // tok+gate+cnt+cnt2

  // ---- arena (phase A = attention) ----
  size_t arena0 = off;
  u16* nx_h = (u16*)alloc((size_t)TT * 2048 * 2);
  u16* nx_l = (u16*)alloc((size_t)TT * 2048 * 2);
  float* R1 = (float*)alloc((size_t)TT * 4096 * 4);  // q_f(3072) / kvb_f(4096) / attn_f(2048)
  u16* q_h = (u16*)alloc((size_t)TT * 3072 * 2);
  u16* q_l = (u16*)alloc((size_t)TT * 3072 * 2);
  float* kv_f = (float*)alloc((size_t)TT * 640 * 4);
  u16* ckv_h = (u16*)alloc((size_t)TT * 512 * 2);
  u16* ckv_l = (u16*)alloc((size_t)TT * 512 * 2);
  u16* kpe_h = (u16*)alloc((size_t)TT * 64 * 2);
  u16* kpe_l = (u16*)alloc((size_t)TT * 64 * 2);
  u16* kvb_h = (u16*)alloc((size_t)TT * 4096 * 2);
  u16* kvb_l = (u16*)alloc((size_t)TT * 4096 * 2);
  size_t phaseA_end = off;
  // ---- arena (phase B = FFN/MoE, aliases phase A; used only after add_residual) ----
  size_t o2 = arena0;
  auto alloc2 = [&](size_t bytes) -> char* {
    char* p = ws + o2;
    o2 += (bytes + 255) & ~(size_t)255;
    return p;
  };
  u16* w13_all = (u16*)alloc2((size_t)NE * SHI * 2048 * 2);     // 92.3 MB
  u16* w2_all = (u16*)alloc2((size_t)NE * 2048 * MINTER * 2);   // 46.1 MB
  // sub-arena shared by {shared-expert g1/g3/h1} (used first) and
  // {MoE pool g13/h1} (used strictly after, same stream) — aliased to cap footprint.
  char* sub = alloc2((size_t)POOLR * SHI * 2 + (size_t)POOLR * MINTER * 2);  // 77.9 MB
  u16* g13_p = (u16*)sub;                                       // POOLR x 2816
  u16* h1_p = (u16*)(sub + (size_t)POOLR * SHI * 2);            // POOLR x 1408
  u16* g1_b = (u16*)sub;                                        // TT x 2816 (aliases g13_p)
  u16* g3_b = (u16*)(sub + (size_t)TT * SHI * 2);
  u16* h1_b = (u16*)(sub + (size_t)2 * TT * SHI * 2);           // ends at 69.2 MB < 77.9 MB
  size_t phaseB_end = o2;
  size_t total = phaseA_end > phaseB_end ? phaseA_end : phaseB_end;
  if (ws_size < total) return;  // insufficient scratch -> fail loud

  float* q_f = R1;     // TT x 3072
  float* kvb_f = R1;   // TT x 4096 (after q split)
  float* attn_f = R1;  // TT x 2048 (after kvb split)

  // ---- weight converts (attention + shared; expert weights converted in phase B) ----
  split_f32<<<(3072 * 2048) / 256, 256, 0, stream>>>(wq, wq_h, wq_l, 3072 * 2048);
  split_wkva<<<(640 * 2048) / 256, 256, 0, stream>>>(wkva, wkva_h, wkva_l);
  split_f32<<<(4096 * 512) / 256, 256, 0, stream>>>(wkvb, wkvb_h, wkvb_l, 4096 * 512);
  split_f32<<<(2048 * 2048) / 256, 256, 0, stream>>>(wo, wo_h, wo_l, 2048 * 2048);
  cvt3_bf16<<<(2816 * 2048) / 256, 256, 0, stream>>>(sw1, sw3, sw2, sw1_b, sw3_b, sw2_b, 2816 * 2048);

  // ---- attention path (split-bf16, f32-grade) ----
  rmsnorm_split<<<TT, 256, 0, stream>>>(x, attn_w, nx_h, nx_l);
  gemm_bt<EPI_F32><<<dim3(24, 32), 256, 0, stream>>>(nx_h, wq_h, q_f, TT, 3072, 2048);
  gemm_bt<EPI_ADD><<<dim3(24, 32), 256, 0, stream>>>(nx_h, wq_l, q_f, TT, 3072, 2048);
  gemm_bt<EPI_ADD><<<dim3(24, 32), 256, 0, stream>>>(nx_l, wq_h, q_f, TT, 3072, 2048);
  rope_qf<<<(TT * NH * 32) / 256, 256, 0, stream>>>(q_f, fcos, fsin);
  split_f32<<<(TT * 3072) / 256, 256, 0, stream>>>(q_f, q_h, q_l, TT * 3072);
  gemm_bt<EPI_F32><<<dim3(5, 32), 256, 0, stream>>>(nx_h, wkva_h, kv_f, TT, 640, 2048);
  gemm_bt<EPI_ADD><<<dim3(5, 32), 256, 0, stream>>>(nx_h, wkva_l, kv_f, TT, 640, 2048);
  gemm_bt<EPI_ADD><<<dim3(5, 32), 256, 0, stream>>>(nx_l, wkva_h, kv_f, TT, 640, 2048);
  kv_norm_rope_split<<<TT, 256, 0, stream>>>(kv_f, kvnw, fcos, fsin, ckv_h, ckv_l, kpe_h, kpe_l);
  gemm_bt<EPI_F32><<<dim3(32, 32), 256, 0, stream>>>(ckv_h, wkvb_h, kvb_f, TT, 4096, 512);
  gemm_bt<EPI_ADD><<<dim3(32, 32), 256, 0, stream>>>(ckv_h, wkvb_l, kvb_f, TT, 4096, 512);
  gemm_bt<EPI_ADD><<<dim3(32, 32), 256, 0, stream>>>(ckv_l, wkvb_h, kvb_f, TT, 4096, 512);
  split_f32<<<(TT * 4096) / 256, 256, 0, stream>>>(kvb_f, kvb_h, kvb_l, TT * 4096);
  flash_attn_split<<<dim3(SS / 64, BB * NH), 256, 0, stream>>>(q_h, q_l, kvb_h, kvb_l,
                                                               kpe_h, kpe_l, attn_f);
  split_f32<<<(TT * 2048) / 256, 256, 0, stream>>>(attn_f, attn_h, attn_l, TT * 2048);
  gemm_bt<EPI_F32><<<dim3(16, 32), 256, 0, stream>>>(attn_h, wo_h, h_f, TT, 2048, 2048);
  gemm_bt<EPI_ADD><<<dim3(16, 32), 256, 0, stream>>>(attn_h, wo_l, h_f, TT, 2048, 2048);
  gemm_bt<EPI_ADD><<<dim3(16, 32), 256, 0, stream>>>(attn_l, wo_h, h_f, TT, 2048, 2048);
  add_residual<<<(TT * 2048) / 256, 256, 0, stream>>>(h_f, x, out, TT * 2048);

  // ---- FFN path ----
  rmsnorm_bf16<<<TT, 256, 0, stream>>>(h_f, ffnw, nh_b);
  router_f32<<<TT, 256, 0, stream>>>(h_f, ffnw, rw, gates_f);

  // expert weight converts (once, into phase-B arena — safe after add_residual)
  cvt_w13<<<(NE * SHI * 2048) / 256, 256, 0, stream>>>(ew1, ew3, w13_all);
  cvt_bf16<<<(NE * 2048 * MINTER) / 256, 256, 0, stream>>>(ew2, w2_all, NE * 2048 * MINTER);

  // routing compaction
  zero_u32<<<(ZERO_WORDS + 255) / 256, 256, 0, stream>>>((unsigned*)pool_tok, ZERO_WORDS);
  moe_count<<<TT / 256, 256, 0, stream>>>(gates_f, cnt);
  moe_prefix<<<1, 64, 0, stream>>>(cnt, basep);
  moe_assign<<<TT / 256, 256, 0, stream>>>(gates_f, basep, cnt2, pool_tok, pool_gate);

  // shared expert (dense, all tokens) — uses sub-arena BEFORE MoE pool kernels
  gemm_bt<EPI_BF16><<<dim3(22, 32), 256, 0, stream>>>(nh_b, sw1_b, g1_b, TT, SHI, 2048);
  gemm_bt<EPI_BF16><<<dim3(22, 32), 256, 0, stream>>>(nh_b, sw3_b, g3_b, TT, SHI, 2048);
  silu_mul<<<(TT * SHI) / 256, 256, 0, stream>>>(g1_b, g3_b, h1_b, TT * SHI);
  gemm_bt<EPI_ADD><<<dim3(16, 32), 256, 0, stream>>>(h1_b, sw2_b, out, TT, 2048, SHI);

  // sparse MoE: gather-GEMM over compact per-expert pools (aliases sub-arena, runs after)
  gemm_moe_w13<<<dim3(SHI / 128, 32, NE), 256, 0, stream>>>(nh_b, w13_all, g13_p,
                                                            pool_tok, cnt, basep);
  silu_mul_pool<<<dim3((MINTER + 255) / 256, POOLR), 256, 0, stream>>>(g13_p, h1_p, basep);
  gemm_moe_w2<<<dim3(2048 / 128, 32, NE), 256, 0, stream>>>(h1_p, w2_all, out,
                                                            pool_tok, pool_gate, cnt, basep);
}

// Round 3
// 2395.808 us; speedup vs baseline: 1.2851x; 1.2851x over previous
//
#include <hip/hip_runtime.h>
#include <stdint.h>
#include <math.h>

typedef unsigned short u16;
typedef short s16x8 __attribute__((ext_vector_type(8)));
typedef float f32x4 __attribute__((ext_vector_type(4)));

// ---- problem constants ----
#define BB 2
#define SS 2048
#define DIM 2048
#define NH 16
#define NOPE 128
#define ROPED 64
#define VH 128
#define KVR 512
#define NE 8
#define MINTER 1408
#define SHI 2816
#define TT 4096          // B*S
#define QD 192           // NOPE+ROPE
#define POOLR 9216       // max padded token-expert pairs (8192 + 8*128)

__device__ __forceinline__ u16 f2bf(float f) {
  unsigned u = __builtin_bit_cast(unsigned, f);
  u += 0x7fffu + ((u >> 16) & 1u);   // RNE
  return (u16)(u >> 16);
}
__device__ __forceinline__ float bf2f(u16 h) {
  return __builtin_bit_cast(float, ((unsigned)h) << 16);
}
__device__ __forceinline__ void split2(float v, u16& hi, u16& lo) {
  u16 h = f2bf(v);
  hi = h;
  lo = f2bf(v - bf2f(h));
}

// ---------------- converts ----------------
__global__ void split_f32(const float* __restrict__ in, u16* __restrict__ hi,
                          u16* __restrict__ lo, int n) {
  int i = blockIdx.x * 256 + threadIdx.x;
  if (i < n) split2(in[i], hi[i], lo[i]);
}
__global__ void cvt3_bf16(const float* __restrict__ a, const float* __restrict__ b,
                          const float* __restrict__ c, u16* __restrict__ oa,
                          u16* __restrict__ ob, u16* __restrict__ oc, int n) {
  int i = blockIdx.x * 256 + threadIdx.x;
  if (i < n) { oa[i] = f2bf(a[i]); ob[i] = f2bf(b[i]); oc[i] = f2bf(c[i]); }
}
__global__ void cvt_bf16(const float* __restrict__ a, u16* __restrict__ o, int n) {
  int i = blockIdx.x * 256 + threadIdx.x;
  if (i < n) o[i] = f2bf(a[i]);
}
// fused [w1;w3] per-expert conversion: w13[e][row][col], row<1408 -> ew1, else ew3
__global__ void cvt_w13(const float* __restrict__ ew1, const float* __restrict__ ew3,
                        u16* __restrict__ w13) {
  int i = blockIdx.x * 256 + threadIdx.x;     // over 8*2816*2048 = 46137344
  int col = i & 2047;
  int r = i >> 11;                            // e*2816 + row
  int e = r / 2816;
  int row = r - e * 2816;
  float v;
  if (row < MINTER) v = ew1[((size_t)e * MINTER + row) * 2048 + col];
  else              v = ew3[((size_t)e * MINTER + (row - MINTER)) * 2048 + col];
  w13[(size_t)i] = f2bf(v);
}
// wkv_a (576x2048) -> padded 640x2048 split (zero rows 576..639)
__global__ void split_wkva(const float* __restrict__ in, u16* __restrict__ hi,
                           u16* __restrict__ lo) {
  int i = blockIdx.x * 256 + threadIdx.x;  // over 640*2048
  int row = i >> 11;
  float v = (row < 576) ? in[(size_t)row * 2048 + (i & 2047)] : 0.f;
  split2(v, hi[i], lo[i]);
}
__global__ void zero_u32(unsigned* __restrict__ p, int n) {
  int i = blockIdx.x * 256 + threadIdx.x;
  if (i < n) p[i] = 0u;
}

// ---------------- rmsnorm (D=2048) f32 -> split bf16 pair ----------------
__global__ __launch_bounds__(256) void rmsnorm_split(const float* __restrict__ x,
                                                     const float* __restrict__ w,
                                                     u16* __restrict__ oh,
                                                     u16* __restrict__ ol) {
  int t = blockIdx.x;
  const float* xr = x + (size_t)t * DIM;
  float ss = 0.f;
#pragma unroll
  for (int i = 0; i < 8; i++) { float v = xr[threadIdx.x + i * 256]; ss += v * v; }
#pragma unroll
  for (int off = 32; off; off >>= 1) ss += __shfl_xor(ss, off, 64);
  __shared__ float red[4];
  if ((threadIdx.x & 63) == 0) red[threadIdx.x >> 6] = ss;
  __syncthreads();
  ss = red[0] + red[1] + red[2] + red[3];
  float rstd = rsqrtf(ss * (1.f / DIM) + 1e-6f);
#pragma unroll
  for (int i = 0; i < 8; i++) {
    int c = threadIdx.x + i * 256;
    float v = xr[c] * rstd * w[c];
    split2(v, oh[(size_t)t * DIM + c], ol[(size_t)t * DIM + c]);
  }
}

// ---------------- rmsnorm f32 -> bf16 (FFN input) ----------------
__global__ __launch_bounds__(256) void rmsnorm_bf16(const float* __restrict__ x,
                                                    const float* __restrict__ w,
                                                    u16* __restrict__ out) {
  int t = blockIdx.x;
  const float* xr = x + (size_t)t * DIM;
  float ss = 0.f;
#pragma unroll
  for (int i = 0; i < 8; i++) { float v = xr[threadIdx.x + i * 256]; ss += v * v; }
#pragma unroll
  for (int off = 32; off; off >>= 1) ss += __shfl_xor(ss, off, 64);
  __shared__ float red[4];
  if ((threadIdx.x & 63) == 0) red[threadIdx.x >> 6] = ss;
  __syncthreads();
  ss = red[0] + red[1] + red[2] + red[3];
  float rstd = rsqrtf(ss * (1.f / DIM) + 1e-6f);
#pragma unroll
  for (int i = 0; i < 8; i++) {
    int c = threadIdx.x + i * 256;
    out[(size_t)t * DIM + c] = f2bf(xr[c] * rstd * w[c]);
  }
}

// ---------------- kv: rmsnorm(512) + rope(k_pe), f32 in -> split outs ----------------
__global__ __launch_bounds__(256) void kv_norm_rope_split(const float* __restrict__ kv,
                                                          const float* __restrict__ w,
                                                          const float* __restrict__ fcos,
                                                          const float* __restrict__ fsin,
                                                          u16* __restrict__ ckvh,
                                                          u16* __restrict__ ckvl,
                                                          u16* __restrict__ peh,
                                                          u16* __restrict__ pel) {
  int t = blockIdx.x;
  int pos = t & (SS - 1);
  const float* kr = kv + (size_t)t * 640;
  float v0 = kr[threadIdx.x], v1 = kr[threadIdx.x + 256];
  float ss = v0 * v0 + v1 * v1;
#pragma unroll
  for (int off = 32; off; off >>= 1) ss += __shfl_xor(ss, off, 64);
  __shared__ float red[4];
  if ((threadIdx.x & 63) == 0) red[threadIdx.x >> 6] = ss;
  __syncthreads();
  ss = red[0] + red[1] + red[2] + red[3];
  float rstd = rsqrtf(ss * (1.f / KVR) + 1e-6f);
  float a0 = v0 * rstd * w[threadIdx.x];
  float a1 = v1 * rstd * w[threadIdx.x + 256];
  split2(a0, ckvh[(size_t)t * KVR + threadIdx.x], ckvl[(size_t)t * KVR + threadIdx.x]);
  split2(a1, ckvh[(size_t)t * KVR + threadIdx.x + 256], ckvl[(size_t)t * KVR + threadIdx.x + 256]);
  if (threadIdx.x < 32) {
    int i = threadIdx.x;
    float x1 = kr[KVR + 2 * i], x2 = kr[KVR + 2 * i + 1];
    float c = fcos[pos * 32 + i], s = fsin[pos * 32 + i];
    split2(x1 * c - x2 * s, peh[(size_t)t * 64 + 2 * i], pel[(size_t)t * 64 + 2 * i]);
    split2(x1 * s + x2 * c, peh[(size_t)t * 64 + 2 * i + 1], pel[(size_t)t * 64 + 2 * i + 1]);
  }
}

// ---------------- rope on q_pe slices (f32 q, in-place) ----------------
__global__ void rope_qf(float* __restrict__ q, const float* __restrict__ fcos,
                        const float* __restrict__ fsin) {
  int idx = blockIdx.x * 256 + threadIdx.x;  // TT*NH*32
  if (idx >= TT * NH * 32) return;
  int i = idx & 31;
  int rem = idx >> 5;
  int h = rem & 15, t = rem >> 4;
  int pos = t & (SS - 1);
  size_t base = (size_t)t * (NH * QD) + h * QD + NOPE + 2 * i;
  float x1 = q[base], x2 = q[base + 1];
  float c = fcos[pos * 32 + i], s = fsin[pos * 32 + i];
  q[base] = x1 * c - x2 * s;
  q[base + 1] = x1 * s + x2 * c;
}

// ---------------- residual: h += x; out = h ----------------
__global__ void add_residual(float* __restrict__ h, const float* __restrict__ x,
                             float* __restrict__ out, int n) {
  int i = blockIdx.x * 256 + threadIdx.x;
  if (i < n) {
    float v = h[i] + x[i];
    h[i] = v;
    out[i] = v;
  }
}

// ---------------- router, fully f32 from h (inline rmsnorm) ----------------
__global__ __launch_bounds__(256) void router_f32(const float* __restrict__ h,
                                                  const float* __restrict__ wn,
                                                  const float* __restrict__ rw,
                                                  float* __restrict__ gates) {
  int t = blockIdx.x;
  const float* xr = h + (size_t)t * DIM;
  float xv[8];
  float ss = 0.f;
#pragma unroll
  for (int i = 0; i < 8; i++) { xv[i] = xr[threadIdx.x + i * 256]; ss += xv[i] * xv[i]; }
#pragma unroll
  for (int off = 32; off; off >>= 1) ss += __shfl_xor(ss, off, 64);
  __shared__ float red4[4];
  if ((threadIdx.x & 63) == 0) red4[threadIdx.x >> 6] = ss;
  __syncthreads();
  ss = red4[0] + red4[1] + red4[2] + red4[3];
  float rstd = rsqrtf(ss * (1.f / DIM) + 1e-6f);
  float p[8];
#pragma unroll
  for (int e = 0; e < 8; e++) p[e] = 0.f;
#pragma unroll
  for (int i = 0; i < 8; i++) {
    int c = threadIdx.x + i * 256;
    float nv = xv[i] * rstd * wn[c];
#pragma unroll
    for (int e = 0; e < 8; e++) p[e] += nv * rw[e * DIM + c];
  }
  __shared__ float red[8 * 256];
#pragma unroll
  for (int e = 0; e < 8; e++) red[e * 256 + threadIdx.x] = p[e];
  __syncthreads();
  for (int st = 128; st > 0; st >>= 1) {
    if (threadIdx.x < st) {
#pragma unroll
      for (int e = 0; e < 8; e++) red[e * 256 + threadIdx.x] += red[e * 256 + threadIdx.x + st];
    }
    __syncthreads();
  }
  if (threadIdx.x == 0) {
    float lg[8], mx = -1e30f;
#pragma unroll
    for (int e = 0; e < 8; e++) { lg[e] = red[e * 256]; mx = fmaxf(mx, lg[e]); }
#pragma unroll
    for (int e = 0; e < 8; e++) lg[e] = expf(lg[e] - mx);
    int i1 = 0;
#pragma unroll
    for (int e = 1; e < 8; e++) if (lg[e] > lg[i1]) i1 = e;
    int i2 = -1;
#pragma unroll
    for (int e = 0; e < 8; e++) if (e != i1 && (i2 < 0 || lg[e] > lg[i2])) i2 = e;
    float v1 = lg[i1], v2 = lg[i2], vs = v1 + v2;
#pragma unroll
    for (int e = 0; e < 8; e++) gates[t * 8 + e] = 0.f;
    gates[t * 8 + i1] = v1 / vs;
    gates[t * 8 + i2] = v2 / vs;
  }
}

// ---------------- MoE routing compaction (device-side, graph-safe) ----------------
__global__ void moe_count(const float* __restrict__ gates, unsigned* __restrict__ cnt) {
  int t = blockIdx.x * 256 + threadIdx.x;
  if (t >= TT) return;
#pragma unroll
  for (int e = 0; e < 8; e++)
    if (gates[t * 8 + e] > 0.f) atomicAdd(&cnt[e], 1u);
}
__global__ void moe_prefix(const unsigned* __restrict__ cnt, unsigned* __restrict__ base) {
  if (threadIdx.x == 0 && blockIdx.x == 0) {
    unsigned o = 0;
#pragma unroll
    for (int e = 0; e < 8; e++) {
      base[e] = o;
      o += (cnt[e] + 127u) & ~127u;   // 128-pad each expert segment
    }
    base[8] = o;
  }
}
__global__ void moe_assign(const float* __restrict__ gates, const unsigned* __restrict__ base,
                           unsigned* __restrict__ cnt2, int* __restrict__ pool_tok,
                           float* __restrict__ pool_gate) {
  int t = blockIdx.x * 256 + threadIdx.x;
  if (t >= TT) return;
#pragma unroll
  for (int e = 0; e < 8; e++) {
    float g = gates[t * 8 + e];
    if (g > 0.f) {
      unsigned p = atomicAdd(&cnt2[e], 1u);
      pool_tok[base[e] + p] = t;
      pool_gate[base[e] + p] = g;
    }
  }
}

// ---------------- silu(g1)*g3, bf16 in/out ----------------
__global__ void silu_mul(const u16* __restrict__ g1, const u16* __restrict__ g3,
                         u16* __restrict__ out, int n) {
  int i = blockIdx.x * 256 + threadIdx.x;
  if (i < n) {
    float a = bf2f(g1[i]), c = bf2f(g3[i]);
    out[i] = f2bf(a / (1.f + expf(-a)) * c);
  }
}
// silu over fused [g1;g3] pool rows
__global__ void silu_mul_pool(const u16* __restrict__ g13, u16* __restrict__ h1,
                              const unsigned* __restrict__ base) {
  unsigned row = blockIdx.y;
  if (row >= base[8]) return;
  int col = blockIdx.x * 256 + threadIdx.x;
  if (col >= MINTER) return;
  float a = bf2f(g13[(size_t)row * SHI + col]);
  float c = bf2f(g13[(size_t)row * SHI + MINTER + col]);
  h1[(size_t)row * MINTER + col] = f2bf(a / (1.f + expf(-a)) * c);
}

// ---------------- GEMM: C[M,N] = A[M,K] @ W[N,K]^T, bf16 in, f32 acc ----------------
enum { EPI_BF16 = 0, EPI_F32 = 1, EPI_ADD = 3 };

template <int EPI>
__global__ __launch_bounds__(256) void gemm_bt(const u16* __restrict__ A,
                                               const u16* __restrict__ W,
                                               void* __restrict__ C,
                                               int M, int N, int K) {
  __shared__ u16 As[128 * 40];
  __shared__ u16 Ws[128 * 40];
  int tid = threadIdx.x;
  int lane = tid & 63;
  int l16 = lane & 15, quad = lane >> 4;
  int wv = tid >> 6;
  int wrow = wv & 1, wcol = wv >> 1;
  int bm = blockIdx.y * 128, bn = blockIdx.x * 128;
  const u16* Ab = A + (size_t)bm * K;
  const u16* Wb = W + (size_t)bn * K;
  int srow = tid >> 2, scol = (tid & 3) * 8;

  f32x4 acc[4][4];
#pragma unroll
  for (int mt = 0; mt < 4; mt++)
#pragma unroll
    for (int nt = 0; nt < 4; nt++) acc[mt][nt] = (f32x4){0.f, 0.f, 0.f, 0.f};

  for (int k0 = 0; k0 < K; k0 += 32) {
    s16x8 a0 = *(const s16x8*)&Ab[(size_t)srow * K + k0 + scol];
    s16x8 a1 = *(const s16x8*)&Ab[(size_t)(srow + 64) * K + k0 + scol];
    s16x8 w0 = *(const s16x8*)&Wb[(size_t)srow * K + k0 + scol];
    s16x8 w1 = *(const s16x8*)&Wb[(size_t)(srow + 64) * K + k0 + scol];
    __syncthreads();
    *(s16x8*)&As[srow * 40 + scol] = a0;
    *(s16x8*)&As[(srow + 64) * 40 + scol] = a1;
    *(s16x8*)&Ws[srow * 40 + scol] = w0;
    *(s16x8*)&Ws[(srow + 64) * 40 + scol] = w1;
    __syncthreads();
    s16x8 af[4], wf[4];
#pragma unroll
    for (int mt = 0; mt < 4; mt++)
      af[mt] = *(const s16x8*)&As[(wrow * 64 + mt * 16 + l16) * 40 + quad * 8];
#pragma unroll
    for (int nt = 0; nt < 4; nt++)
      wf[nt] = *(const s16x8*)&Ws[(wcol * 64 + nt * 16 + l16) * 40 + quad * 8];
#pragma unroll
    for (int mt = 0; mt < 4; mt++)
#pragma unroll
      for (int nt = 0; nt < 4; nt++)
        acc[mt][nt] = __builtin_amdgcn_mfma_f32_16x16x32_bf16(af[mt], wf[nt], acc[mt][nt], 0, 0, 0);
  }
#pragma unroll
  for (int mt = 0; mt < 4; mt++) {
#pragma unroll
    for (int r = 0; r < 4; r++) {
      int row = bm + wrow * 64 + mt * 16 + quad * 4 + r;
#pragma unroll
      for (int nt = 0; nt < 4; nt++) {
        int col = bn + wcol * 64 + nt * 16 + l16;
        float v = acc[mt][nt][r];
        size_t idx = (size_t)row * N + col;
        if constexpr (EPI == EPI_BF16) ((u16*)C)[idx] = f2bf(v);
        else if constexpr (EPI == EPI_F32) ((float*)C)[idx] = v;
        else ((float*)C)[idx] += v;
      }
    }
  }
}

// ---------------- MoE gather GEMM (w1||w3 fused): g13[pool] = nh[tok] @ w13_e^T ----------------
__global__ __launch_bounds__(256) void gemm_moe_w13(const u16* __restrict__ A,   // nh_b [TT,2048]
                                                    const u16* __restrict__ W,   // w13 [8][2816][2048]
                                                    u16* __restrict__ C,         // g13 pool [POOLR][2816]
                                                    const int* __restrict__ pool_tok,
                                                    const unsigned* __restrict__ cnt,
                                                    const unsigned* __restrict__ base) {
  int e = blockIdx.z;
  int bm = blockIdx.y * 128;
  if ((unsigned)bm >= cnt[e]) return;       // tile fully past this expert's tokens
  int pb = (int)base[e] + bm;
  const int K = 2048;
  __shared__ u16 As[128 * 40];
  __shared__ u16 Ws[128 * 40];
  int tid = threadIdx.x;
  int lane = tid & 63;
  int l16 = lane & 15, quad = lane >> 4;
  int wv = tid >> 6;
  int wrow = wv & 1, wcol = wv >> 1;
  int bn = blockIdx.x * 128;
  const u16* Wb = W + (size_t)e * SHI * 2048 + (size_t)bn * K;
  int srow = tid >> 2, scol = (tid & 3) * 8;
  const u16* Ap0 = A + (size_t)pool_tok[pb + srow] * K;        // gathered rows
  const u16* Ap1 = A + (size_t)pool_tok[pb + srow + 64] * K;

  f32x4 acc[4][4];
#pragma unroll
  for (int mt = 0; mt < 4; mt++)
#pragma unroll
    for (int nt = 0; nt < 4; nt++) acc[mt][nt] = (f32x4){0.f, 0.f, 0.f, 0.f};

  for (int k0 = 0; k0 < K; k0 += 32) {
    s16x8 a0 = *(const s16x8*)&Ap0[k0 + scol];
    s16x8 a1 = *(const s16x8*)&Ap1[k0 + scol];
    s16x8 w0 = *(const s16x8*)&Wb[(size_t)srow * K + k0 + scol];
    s16x8 w1 = *(const s16x8*)&Wb[(size_t)(srow + 64) * K + k0 + scol];
    __syncthreads();
    *(s16x8*)&As[srow * 40 + scol] = a0;
    *(s16x8*)&As[(srow + 64) * 40 + scol] = a1;
    *(s16x8*)&Ws[srow * 40 + scol] = w0;
    *(s16x8*)&Ws[(srow + 64) * 40 + scol] = w1;
    __syncthreads();
    s16x8 af[4], wf[4];
#pragma unroll
    for (int mt = 0; mt < 4; mt++)
      af[mt] = *(const s16x8*)&As[(wrow * 64 + mt * 16 + l16) * 40 + quad * 8];
#pragma unroll
    for (int nt = 0; nt < 4; nt++)
      wf[nt] = *(const s16x8*)&Ws[(wcol * 64 + nt * 16 + l16) * 40 + quad * 8];
#pragma unroll
    for (int mt = 0; mt < 4; mt++)
#pragma unroll
      for (int nt = 0; nt < 4; nt++)
        acc[mt][nt] = __builtin_amdgcn_mfma_f32_16x16x32_bf16(af[mt], wf[nt], acc[mt][nt], 0, 0, 0);
  }
#pragma unroll
  for (int mt = 0; mt < 4; mt++) {
#pragma unroll
    for (int r = 0; r < 4; r++) {
      int row = pb + wrow * 64 + mt * 16 + quad * 4 + r;
#pragma unroll
      for (int nt = 0; nt < 4; nt++) {
        int col = bn + wcol * 64 + nt * 16 + l16;
        C[(size_t)row * SHI + col] = f2bf(acc[mt][nt][r]);
      }
    }
  }
}

// ---------------- MoE down-proj GEMM with gated atomic scatter into out ----------------
__global__ __launch_bounds__(256) void gemm_moe_w2(const u16* __restrict__ A,   // h1 pool [POOLR][1408]
                                                   const u16* __restrict__ W,   // w2 [8][2048][1408]
                                                   float* __restrict__ out,     // [TT][2048]
                                                   const int* __restrict__ pool_tok,
                                                   const float* __restrict__ pool_gate,
                                                   const unsigned* __restrict__ cnt,
                                                   const unsigned* __restrict__ base) {
  int e = blockIdx.z;
  int bm = blockIdx.y * 128;
  if ((unsigned)bm >= cnt[e]) return;
  int pb = (int)base[e] + bm;
  const int K = MINTER;  // 1408
  __shared__ u16 As[128 * 40];
  __shared__ u16 Ws[128 * 40];
  int tid = threadIdx.x;
  int lane = tid & 63;
  int l16 = lane & 15, quad = lane >> 4;
  int wv = tid >> 6;
  int wrow = wv & 1, wcol = wv >> 1;
  int bn = blockIdx.x * 128;
  const u16* Ab = A + (size_t)pb * K;
  const u16* Wb = W + (size_t)e * 2048 * MINTER + (size_t)bn * K;
  int srow = tid >> 2, scol = (tid & 3) * 8;

  f32x4 acc[4][4];
#pragma unroll
  for (int mt = 0; mt < 4; mt++)
#pragma unroll
    for (int nt = 0; nt < 4; nt++) acc[mt][nt] = (f32x4){0.f, 0.f, 0.f, 0.f};

  for (int k0 = 0; k0 < K; k0 += 32) {
    s16x8 a0 = *(const s16x8*)&Ab[(size_t)srow * K + k0 + scol];
    s16x8 a1 = *(const s16x8*)&Ab[(size_t)(srow + 64) * K + k0 + scol];
    s16x8 w0 = *(const s16x8*)&Wb[(size_t)srow * K + k0 + scol];
    s16x8 w1 = *(const s16x8*)&Wb[(size_t)(srow + 64) * K + k0 + scol];
    __syncthreads();
    *(s16x8*)&As[srow * 40 + scol] = a0;
    *(s16x8*)&As[(srow + 64) * 40 + scol] = a1;
    *(s16x8*)&Ws[srow * 40 + scol] = w0;
    *(s16x8*)&Ws[(srow + 64) * 40 + scol] = w1;
    __syncthreads();
    s16x8 af[4], wf[4];
#pragma unroll
    for (int mt = 0; mt < 4; mt++)
      af[mt] = *(const s16x8*)&As[(wrow * 64 + mt * 16 + l16) * 40 + quad * 8];
#pragma unroll
    for (int nt = 0; nt < 4; nt++)
      wf[nt] = *(const s16x8*)&Ws[(wcol * 64 + nt * 16 + l16) * 40 + quad * 8];
#pragma unroll
    for (int mt = 0; mt < 4; mt++)
#pragma unroll
      for (int nt = 0; nt < 4; nt++)
        acc[mt][nt] = __builtin_amdgcn_mfma_f32_16x16x32_bf16(af[mt], wf[nt], acc[mt][nt], 0, 0, 0);
  }
#pragma unroll
  for (int mt = 0; mt < 4; mt++) {
#pragma unroll
    for (int r = 0; r < 4; r++) {
      int prow = pb + wrow * 64 + mt * 16 + quad * 4 + r;
      float g = pool_gate[prow];
      int tok = pool_tok[prow];
      if (g > 0.f) {   // padding rows have gate==0 -> no store, no race
#pragma unroll
        for (int nt = 0; nt < 4; nt++) {
          int col = bn + wcol * 64 + nt * 16 + l16;
          unsafeAtomicAdd(&out[(size_t)tok * 2048 + col], g * acc[mt][nt][r]);
        }
      }
    }
  }
}

// ---------------- flash attention v2: split-K chunks + prefetch + 2 barriers/tile ----
// grid (48, 32): bx<16 -> chunk0 of qt=31-bx; bx in [16,32) -> chunk1 of qt=47-bx;
// bx>=32 -> qt=47-bx (<16, single chunk). Chunk = 32 k-tiles (1024 keys).
// qt<16: write final attn_h/attn_l directly. qt>=16: write unnormalized partials+m,l.
__global__ __launch_bounds__(256) void flash_attn_split(
    const u16* __restrict__ Qh, const u16* __restrict__ Ql,
    const u16* __restrict__ KVh, const u16* __restrict__ KVl,
    const u16* __restrict__ Peh, const u16* __restrict__ Pel,
    u16* __restrict__ attnh, u16* __restrict__ attnl,
    float* __restrict__ opart, float* __restrict__ ml) {
  __shared__ u16 Ksh[32 * 200], Ksl[32 * 200];
  __shared__ u16 Vth[128 * 40], Vtl[128 * 40];
  __shared__ u16 Psh[64 * 40], Psl[64 * 40];
  int tid = threadIdx.x;
  int lane = tid & 63, wv = tid >> 6;
  int l16 = lane & 15, quad = lane >> 4;
  int bx = blockIdx.x;
  int qt, chunk;
  if (bx < 16) { qt = 31 - bx; chunk = 0; }
  else if (bx < 32) { qt = 47 - bx; chunk = 1; }
  else { qt = 47 - bx; chunk = 0; }
  int bh = blockIdx.y;
  int b = bh >> 4, h = bh & 15;
  int tb = b * SS;
  int nkt = 2 * qt + 2;
  int t0 = chunk * 32;
  int t1 = nkt < t0 + 32 ? nkt : t0 + 32;
  const float kSc = 0.07216878364870322f * 1.4426950408889634f;  // 1/sqrt(192)*log2(e)

  s16x8 qfh[6], qfl[6];
  {
    int qrow = tb + qt * 64 + wv * 16 + l16;
    const u16* ph = Qh + (size_t)qrow * (NH * QD) + h * QD;
    const u16* pl = Ql + (size_t)qrow * (NH * QD) + h * QD;
#pragma unroll
    for (int s = 0; s < 6; s++) {
      qfh[s] = *(const s16x8*)&ph[s * 32 + quad * 8];
      qfl[s] = *(const s16x8*)&pl[s * 32 + quad * 8];
    }
  }
  float m_i[4], l_i[4];
#pragma unroll
  for (int r = 0; r < 4; r++) { m_i[r] = -1e30f; l_i[r] = 0.f; }
  f32x4 o_acc[8];
#pragma unroll
  for (int nt = 0; nt < 8; nt++) o_acc[nt] = (f32x4){0.f, 0.f, 0.f, 0.f};

  // staging registers (prefetch)
  s16x8 rkh[2], rkl[2], rph, rpl;
  unsigned rvh[8], rvl[8];
  int st_row = tid >> 4, st_cc = (tid & 15) * 8;         // K nope (with +16 row for i=1)
  int pe_row = tid >> 3, pe_cc = (tid & 7) * 8;          // K pe

  auto LOADT = [&](int kt) {
    int krow = tb + kt * 32;
#pragma unroll
    for (int i = 0; i < 2; i++) {
      size_t g = (size_t)(krow + st_row + i * 16) * 4096 + h * 256 + st_cc;
      rkh[i] = *(const s16x8*)&KVh[g];
      rkl[i] = *(const s16x8*)&KVl[g];
    }
    {
      size_t g = (size_t)(krow + pe_row) * 64 + pe_cc;
      rph = *(const s16x8*)&Peh[g];
      rpl = *(const s16x8*)&Pel[g];
    }
#pragma unroll
    for (int i = 0; i < 8; i++) {
      int idx = tid + i * 256;
      int n2 = idx & 63, k = idx >> 6;
      size_t g = (size_t)(krow + k) * 4096 + h * 256 + 128 + n2 * 2;
      rvh[i] = *(const unsigned*)&KVh[g];
      rvl[i] = *(const unsigned*)&KVl[g];
    }
  };
  auto STORET = [&]() {
#pragma unroll
    for (int i = 0; i < 2; i++) {
      *(s16x8*)&Ksh[(st_row + i * 16) * 200 + st_cc] = rkh[i];
      *(s16x8*)&Ksl[(st_row + i * 16) * 200 + st_cc] = rkl[i];
    }
    *(s16x8*)&Ksh[pe_row * 200 + 128 + pe_cc] = rph;
    *(s16x8*)&Ksl[pe_row * 200 + 128 + pe_cc] = rpl;
#pragma unroll
    for (int i = 0; i < 8; i++) {
      int idx = tid + i * 256;
      int n2 = idx & 63, k = idx >> 6;
      unsigned vh = rvh[i], vl = rvl[i];
      Vth[(2 * n2) * 40 + k] = (u16)vh;
      Vth[(2 * n2 + 1) * 40 + k] = (u16)(vh >> 16);
      Vtl[(2 * n2) * 40 + k] = (u16)vl;
      Vtl[(2 * n2 + 1) * 40 + k] = (u16)(vl >> 16);
    }
  };

  LOADT(t0);
  for (int kt = t0; kt < t1; kt++) {
    __syncthreads();          // previous tile's LDS reads complete
    STORET();
    __syncthreads();          // staging visible
    if (kt + 1 < t1) LOADT(kt + 1);   // prefetch next tile under compute
    f32x4 sc[2];
#pragma unroll
    for (int ct = 0; ct < 2; ct++) {
      f32x4 a = (f32x4){0.f, 0.f, 0.f, 0.f};
#pragma unroll
      for (int s = 0; s < 6; s++) {
        s16x8 kh = *(const s16x8*)&Ksh[(ct * 16 + l16) * 200 + s * 32 + quad * 8];
        s16x8 kl = *(const s16x8*)&Ksl[(ct * 16 + l16) * 200 + s * 32 + quad * 8];
        a = __builtin_amdgcn_mfma_f32_16x16x32_bf16(qfh[s], kh, a, 0, 0, 0);
        a = __builtin_amdgcn_mfma_f32_16x16x32_bf16(qfh[s], kl, a, 0, 0, 0);
        a = __builtin_amdgcn_mfma_f32_16x16x32_bf16(qfl[s], kh, a, 0, 0, 0);
      }
      sc[ct] = a;
    }
    float rowmax[4];
#pragma unroll
    for (int r = 0; r < 4; r++) rowmax[r] = -1e30f;
#pragma unroll
    for (int ct = 0; ct < 2; ct++) {
#pragma unroll
      for (int r = 0; r < 4; r++) {
        float v = sc[ct][r] * kSc;
        int kg = kt * 32 + ct * 16 + l16;
        int qg = qt * 64 + wv * 16 + quad * 4 + r;
        if (kg > qg) v = -1e30f;
        sc[ct][r] = v;
        rowmax[r] = fmaxf(rowmax[r], v);
      }
    }
#pragma unroll
    for (int r = 0; r < 4; r++) {
      float v = rowmax[r];
#pragma unroll
      for (int off = 1; off < 16; off <<= 1) v = fmaxf(v, __shfl_xor(v, off, 64));
      rowmax[r] = v;
    }
    float alpha[4], rs[4];
#pragma unroll
    for (int r = 0; r < 4; r++) {
      float mn = fmaxf(m_i[r], rowmax[r]);
      alpha[r] = exp2f(m_i[r] - mn);
      m_i[r] = mn;
      rs[r] = 0.f;
    }
#pragma unroll
    for (int ct = 0; ct < 2; ct++) {
#pragma unroll
      for (int r = 0; r < 4; r++) {
        float p = exp2f(sc[ct][r] - m_i[r]);
        rs[r] += p;
        int prow = (wv * 16 + quad * 4 + r) * 40 + ct * 16 + l16;
        u16 hb = f2bf(p);
        Psh[prow] = hb;
        Psl[prow] = f2bf(p - bf2f(hb));
      }
    }
#pragma unroll
    for (int r = 0; r < 4; r++) {
      float v = rs[r];
#pragma unroll
      for (int off = 1; off < 16; off <<= 1) v += __shfl_xor(v, off, 64);
      l_i[r] = l_i[r] * alpha[r] + v;
    }
#pragma unroll
    for (int nt = 0; nt < 8; nt++)
#pragma unroll
      for (int r = 0; r < 4; r++) o_acc[nt][r] *= alpha[r];
    // NOTE: no barrier here — P rows are wave-private; V already barriered post-stage.
    s16x8 pfh = *(const s16x8*)&Psh[(wv * 16 + l16) * 40 + quad * 8];
    s16x8 pfl = *(const s16x8*)&Psl[(wv * 16 + l16) * 40 + quad * 8];
#pragma unroll
    for (int nt = 0; nt < 8; nt++) {
      s16x8 vh = *(const s16x8*)&Vth[(nt * 16 + l16) * 40 + quad * 8];
      s16x8 vl = *(const s16x8*)&Vtl[(nt * 16 + l16) * 40 + quad * 8];
      o_acc[nt] = __builtin_amdgcn_mfma_f32_16x16x32_bf16(pfh, vh, o_acc[nt], 0, 0, 0);
      o_acc[nt] = __builtin_amdgcn_mfma_f32_16x16x32_bf16(pfh, vl, o_acc[nt], 0, 0, 0);
      o_acc[nt] = __builtin_amdgcn_mfma_f32_16x16x32_bf16(pfl, vh, o_acc[nt], 0, 0, 0);
    }
  }
  if (qt < 16) {
    // single chunk: final output, split to bf16 pair directly
#pragma unroll
    for (int r = 0; r < 4; r++) {
      int trow = tb + qt * 64 + wv * 16 + quad * 4 + r;
      float inv_l = 1.f / l_i[r];
      size_t ob = (size_t)trow * 2048 + h * 128;
#pragma unroll
      for (int nt = 0; nt < 8; nt++) {
        float v = o_acc[nt][r] * inv_l;
        u16 hi2, lo2;
        split2(v, hi2, lo2);
        attnh[ob + nt * 16 + l16] = hi2;
        attnl[ob + nt * 16 + l16] = lo2;
      }
    }
  } else {
    int pbase = (chunk * 32 + bh) * 2048;
#pragma unroll
    for (int r = 0; r < 4; r++) {
      int pos = qt * 64 + wv * 16 + quad * 4 + r;
      size_t ob = ((size_t)pbase + pos) * 128;
#pragma unroll
      for (int nt = 0; nt < 8; nt++) opart[ob + nt * 16 + l16] = o_acc[nt][r];
      if (l16 == 0) {
        ml[((size_t)pbase + pos) * 2] = m_i[r];
        ml[((size_t)pbase + pos) * 2 + 1] = l_i[r];
      }
    }
  }
}

// ---------------- combine 2 split-K chunks (rows with pos >= 1024) ----------------
__global__ __launch_bounds__(256) void attn_combine(const float* __restrict__ opart,
                                                    const float* __restrict__ ml,
                                                    u16* __restrict__ attnh,
                                                    u16* __restrict__ attnl) {
  int rr = blockIdx.x * 2 + (threadIdx.x >> 7);   // over 32 bh x 1024 pos
  int col = threadIdx.x & 127;
  int bh = rr >> 10;
  int pos = 1024 + (rr & 1023);
  int b = bh >> 4, h = bh & 15;
  size_t i0 = (size_t)bh * 2048 + pos;
  size_t i1 = (size_t)(32 + bh) * 2048 + pos;
  float m0 = ml[i0 * 2], l0 = ml[i0 * 2 + 1];
  float m1 = ml[i1 * 2], l1 = ml[i1 * 2 + 1];
  float M = fmaxf(m0, m1);
  float a0 = exp2f(m0 - M), a1 = exp2f(m1 - M);
  float L = l0 * a0 + l1 * a1;
  float v = (opart[i0 * 128 + col] * a0 + opart[i1 * 128 + col] * a1) / L;
  size_t o = ((size_t)(b * 2048 + pos)) * 2048 + h * 128 + col;
  u16 hi2, lo2;
  split2(v, hi2, lo2);
  attnh[o] = hi2;
  attnl[o] = lo2;
}

// ---------------- host ----------------
extern "C" void kernel_launch(void* const* d_in, const int* in_sizes, int n_in,
                              void* d_out, int out_size, void* d_ws, size_t ws_size,
                              hipStream_t stream) {
  const float* x = (const float*)d_in[0];
  const float* fcos = (const float*)d_in[1];
  const float* fsin = (const float*)d_in[2];
  const float* attn_w = (const float*)d_in[3];
  const float* wq = (const float*)d_in[4];
  const float* wkva = (const float*)d_in[5];
  const float* kvnw = (const float*)d_in[6];
  const float* wkvb = (const float*)d_in[7];
  const float* wo = (const float*)d_in[8];
  const float* ffnw = (const float*)d_in[9];
  const float* rw = (const float*)d_in[10];
  const float* ew1 = (const float*)d_in[11];
  const float* ew3 = (const float*)d_in[12];
  const float* ew2 = (const float*)d_in[13];
  const float* sw1 = (const float*)d_in[14];
  const float* sw3 = (const float*)d_in[15];
  const float* sw2 = (const float*)d_in[16];
  float* out = (float*)d_out;

  char* ws = (char*)d_ws;
  size_t off = 0;
  auto alloc = [&](size_t bytes) -> char* {
    char* p = ws + off;
    off += (bytes + 255) & ~(size_t)255;
    return p;
  };
  // ---- persistent ----
  u16* wq_h = (u16*)alloc((size_t)3072 * 2048 * 2);
  u16* wq_l = (u16*)alloc((size_t)3072 * 2048 * 2);
  u16* wkva_h = (u16*)alloc((size_t)640 * 2048 * 2);
  u16* wkva_l = (u16*)alloc((size_t)640 * 2048 * 2);
  u16* wkvb_h = (u16*)alloc((size_t)4096 * 512 * 2);
  u16* wkvb_l = (u16*)alloc((size_t)4096 * 512 * 2);
  u16* wo_h = (u16*)alloc((size_t)2048 * 2048 * 2);
  u16* wo_l = (u16*)alloc((size_t)2048 * 2048 * 2);
  u16* sw1_b = (u16*)alloc((size_t)2816 * 2048 * 2);
  u16* sw3_b = (u16*)alloc((size_t)2816 * 2048 * 2);
  u16* sw2_b = (u16*)alloc((size_t)2048 * 2816 * 2);
  float* h_f = (float*)alloc((size_t)TT * 2048 * 4);
  u16* nh_b = (u16*)alloc((size_t)TT * 2048 * 2);
  float* gates_f = (float*)alloc((size_t)TT * 8 * 4);
  u16* attn_h = (u16*)alloc((size_t)TT * 2048 * 2);
  u16* attn_l = (u16*)alloc((size_t)TT * 2048 * 2);
  // routing pool (contiguous for one-shot zeroing: tok, gate, cnt, cnt2)
  int* pool_tok = (int*)alloc((size_t)POOLR * 4);      // 36864 B (256-aligned)
  float* pool_gate = (float*)alloc((size_t)POOLR * 4); // 36864 B
  unsigned* cnt = (unsigned*)alloc(32);                // -> 256 B
  unsigned* cnt2 = (unsigned*)alloc(32);               // -> 256 B
  unsigned* basep = (unsigned*)alloc(64);              // written fully by moe_prefix
  const int ZERO_WORDS = (36864 + 36864 + 256 + 256) / 4;  // tok+gate+cnt+cnt2

  // ---- arena (phase A = attention) ----
  size_t arena0 = off;
  u16* nx_h = (u16*)alloc((size_t)TT * 2048 * 2);
  u16* nx_l = (u16*)alloc((size_t)TT * 2048 * 2);
  float* R1 = (float*)alloc((size_t)TT * 4096 * 4);  // q_f(3072) / kvb_f(4096) / opart(2*32*2048*128)
  u16* q_h = (u16*)alloc((size_t)TT * 3072 * 2);
  u16* q_l = (u16*)alloc((size_t)TT * 3072 * 2);
  float* kv_f = (float*)alloc((size_t)TT * 640 * 4);  // kv pre-norm / ml(2*32*2048*2) later
  u16* ckv_h = (u16*)alloc((size_t)TT * 512 * 2);
  u16* ckv_l = (u16*)alloc((size_t)TT * 512 * 2);
  u16* kpe_h = (u16*)alloc((size_t)TT * 64 * 2);
  u16* kpe_l = (u16*)alloc((size_t)TT * 64 * 2);
  u16* kvb_h = (u16*)alloc((size_t)TT * 4096 * 2);
  u16* kvb_l = (u16*)alloc((size_t)TT * 4096 * 2);
  size_t phaseA_end = off;
  // ---- arena (phase B = FFN/MoE, aliases phase A; used only after add_residual) ----
  size_t o2 = arena0;
  auto alloc2 = [&](size_t bytes) -> char* {
    char* p = ws + o2;
    o2 += (bytes + 255) & ~(size_t)255;
    return p;
  };
  u16* w13_all = (u16*)alloc2((size_t)NE * SHI * 2048 * 2);     // 92.3 MB
  u16* w2_all = (u16*)alloc2((size_t)NE * 2048 * MINTER * 2);   // 46.1 MB
  // sub-arena shared by {shared-expert g1/g3/h1} (used first) and
  // {MoE pool g13/h1} (used strictly after, same stream) — aliased to cap footprint.
  char* sub = alloc2((size_t)POOLR * SHI * 2 + (size_t)POOLR * MINTER * 2);  // 77.9 MB
  u16* g13_p = (u16*)sub;                                       // POOLR x 2816
  u16* h1_p = (u16*)(sub + (size_t)POOLR * SHI * 2);            // POOLR x 1408
  u16* g1_b = (u16*)sub;                                        // TT x 2816 (aliases g13_p)
  u16* g3_b = (u16*)(sub + (size_t)TT * SHI * 2);
  u16* h1_b = (u16*)(sub + (size_t)2 * TT * SHI * 2);           // ends at 69.2 MB < 77.9 MB
  size_t phaseB_end = o2;
  size_t total = phaseA_end > phaseB_end ? phaseA_end : phaseB_end;
  if (ws_size < total) return;  // insufficient scratch -> fail loud

  float* q_f = R1;     // TT x 3072
  float* kvb_f = R1;   // TT x 4096 (after q split)
  float* opart = R1;   // [2][32][2048][128] f32 attention partials (after kvb split)
  float* ml_f = kv_f;  // [2][32][2048][2] f32 (kv_f dead after kv_norm_rope_split)

  // ---- weight converts (attention + shared; expert weights converted in phase B) ----
  split_f32<<<(3072 * 2048) / 256, 256, 0, stream>>>(wq, wq_h, wq_l, 3072 * 2048);
  split_wkva<<<(640 * 2048) / 256, 256, 0, stream>>>(wkva, wkva_h, wkva_l);
  split_f32<<<(4096 * 512) / 256, 256, 0, stream>>>(wkvb, wkvb_h, wkvb_l, 4096 * 512);
  split_f32<<<(2048 * 2048) / 256, 256, 0, stream>>>(wo, wo_h, wo_l, 2048 * 2048);
  cvt3_bf16<<<(2816 * 2048) / 256, 256, 0, stream>>>(sw1, sw3, sw2, sw1_b, sw3_b, sw2_b, 2816 * 2048);

  // ---- attention path (split-bf16, f32-grade) ----
  rmsnorm_split<<<TT, 256, 0, stream>>>(x, attn_w, nx_h, nx_l);
  gemm_bt<EPI_F32><<<dim3(24, 32), 256, 0, stream>>>(nx_h, wq_h, q_f, TT, 3072, 2048);
  gemm_bt<EPI_ADD><<<dim3(24, 32), 256, 0, stream>>>(nx_h, wq_l, q_f, TT, 3072, 2048);
  gemm_bt<EPI_ADD><<<dim3(24, 32), 256, 0, stream>>>(nx_l, wq_h, q_f, TT, 3072, 2048);
  rope_qf<<<(TT * NH * 32) / 256, 256, 0, stream>>>(q_f, fcos, fsin);
  split_f32<<<(TT * 3072) / 256, 256, 0, stream>>>(q_f, q_h, q_l, TT * 3072);
  gemm_bt<EPI_F32><<<dim3(5, 32), 256, 0, stream>>>(nx_h, wkva_h, kv_f, TT, 640, 2048);
  gemm_bt<EPI_ADD><<<dim3(5, 32), 256, 0, stream>>>(nx_h, wkva_l, kv_f, TT, 640, 2048);
  gemm_bt<EPI_ADD><<<dim3(5, 32), 256, 0, stream>>>(nx_l, wkva_h, kv_f, TT, 640, 2048);
  kv_norm_rope_split<<<TT, 256, 0, stream>>>(kv_f, kvnw, fcos, fsin, ckv_h, ckv_l, kpe_h, kpe_l);
  gemm_bt<EPI_F32><<<dim3(32, 32), 256, 0, stream>>>(ckv_h, wkvb_h, kvb_f, TT, 4096, 512);
  gemm_bt<EPI_ADD><<<dim3(32, 32), 256, 0, stream>>>(ckv_h, wkvb_l, kvb_f, TT, 4096, 512);
  gemm_bt<EPI_ADD><<<dim3(32, 32), 256, 0, stream>>>(ckv_l, wkvb_h, kvb_f, TT, 4096, 512);
  split_f32<<<(TT * 4096) / 256, 256, 0, stream>>>(kvb_f, kvb_h, kvb_l, TT * 4096);
  // flash attention: split-K chunks write attn_h/attn_l (qt<16) or partials (qt>=16)
  flash_attn_split<<<dim3(48, BB * NH), 256, 0, stream>>>(q_h, q_l, kvb_h, kvb_l,
                                                          kpe_h, kpe_l,
                                                          attn_h, attn_l, opart, ml_f);
  attn_combine<<<(32 * 1024) / 2, 256, 0, stream>>>(opart, ml_f, attn_h, attn_l);
  gemm_bt<EPI_F32><<<dim3(16, 32), 256, 0, stream>>>(attn_h, wo_h, h_f, TT, 2048, 2048);
  gemm_bt<EPI_ADD><<<dim3(16, 32), 256, 0, stream>>>(attn_h, wo_l, h_f, TT, 2048, 2048);
  gemm_bt<EPI_ADD><<<dim3(16, 32), 256, 0, stream>>>(attn_l, wo_h, h_f, TT, 2048, 2048);
  add_residual<<<(TT * 2048) / 256, 256, 0, stream>>>(h_f, x, out, TT * 2048);

  // ---- FFN path ----
  rmsnorm_bf16<<<TT, 256, 0, stream>>>(h_f, ffnw, nh_b);
  router_f32<<<TT, 256, 0, stream>>>(h_f, ffnw, rw, gates_f);

  // expert weight converts (once, into phase-B arena — safe after add_residual)
  cvt_w13<<<(NE * SHI * 2048) / 256, 256, 0, stream>>>(ew1, ew3, w13_all);
  cvt_bf16<<<(NE * 2048 * MINTER) / 256, 256, 0, stream>>>(ew2, w2_all, NE * 2048 * MINTER);

  // routing compaction
  zero_u32<<<(ZERO_WORDS + 255) / 256, 256, 0, stream>>>((unsigned*)pool_tok, ZERO_WORDS);
  moe_count<<<TT / 256, 256, 0, stream>>>(gates_f, cnt);
  moe_prefix<<<1, 64, 0, stream>>>(cnt, basep);
  moe_assign<<<TT / 256, 256, 0, stream>>>(gates_f, basep, cnt2, pool_tok, pool_gate);

  // shared expert (dense, all tokens) — uses sub-arena BEFORE MoE pool kernels
  gemm_bt<EPI_BF16><<<dim3(22, 32), 256, 0, stream>>>(nh_b, sw1_b, g1_b, TT, SHI, 2048);
  gemm_bt<EPI_BF16><<<dim3(22, 32), 256, 0, stream>>>(nh_b, sw3_b, g3_b, TT, SHI, 2048);
  silu_mul<<<(TT * SHI) / 256, 256, 0, stream>>>(g1_b, g3_b, h1_b, TT * SHI);
  gemm_bt<EPI_ADD><<<dim3(16, 32), 256, 0, stream>>>(h1_b, sw2_b, out, TT, 2048, SHI);

  // sparse MoE: gather-GEMM over compact per-expert pools (aliases sub-arena, runs after)
  gemm_moe_w13<<<dim3(SHI / 128, 32, NE), 256, 0, stream>>>(nh_b, w13_all, g13_p,
                                                            pool_tok, cnt, basep);
  silu_mul_pool<<<dim3((MINTER + 255) / 256, POOLR), 256, 0, stream>>>(g13_p, h1_p, basep);
  gemm_moe_w2<<<dim3(2048 / 128, 32, NE), 256, 0, stream>>>(h1_p, w2_all, out,
                                                            pool_tok, pool_gate, cnt, basep);
}